// Round 6
// baseline (624.790 us; speedup 1.0000x reference)
//
#include <hip/hip_runtime.h>

// ---------------------------------------------------------------------------
// SpatioTemporalBlock: biLSTM -> temporal MHA -> (collapsed) GAT -> fusion
// B=16 S=128 F=64 H=256 HEADS=4 DH=64 AH=128 D2=512
// FP32 inputs/outputs; MFMA operands converted f32->bf16 at staging.
// GAT collapses: broadcast node features => uniform alpha => dense layers.
//
// LSTM: one WAVE per WG (64 thr), 32 WGs (dir d, chunk q: h-cols q*16..+15,
// 64 gate rows). Whh/Wih bf16 in wave-private LDS. Poison-word sync: hbuf is
// a write-once ring [128][2][16][128] u32 (memset 0xFF). Readers poll 8
// dwordx4 sc1 loads per lane, laid out to BE the MFMA A-fragments; one wave
// computes all 4 gate N-tiles so i/f/g/o for a (batch,col) share a lane ->
// zero barriers, zero cross-wave traffic in the 128-step loop.
// ---------------------------------------------------------------------------

typedef unsigned short u16;
typedef unsigned int u32;
typedef __bf16 bf16x8 __attribute__((ext_vector_type(8)));
typedef float f32x4 __attribute__((ext_vector_type(4)));
typedef unsigned short ushort8v __attribute__((ext_vector_type(8)));
typedef unsigned int uint4v __attribute__((ext_vector_type(4)));

#define BN_INV_F 0.9999950000374997f
#define POISON 0xFFFFFFFFu

__device__ __forceinline__ float b2f(u16 u) {
  union { float f; unsigned int i; } v;
  v.i = ((unsigned int)u) << 16;
  return v.f;
}
__device__ __forceinline__ u16 f2b(float f) {
  union { float f; unsigned int i; } v;
  v.f = f;
  unsigned int x = v.i;
  unsigned int r = (x + 0x7FFFu + ((x >> 16) & 1u)) >> 16;
  return (u16)r;
}
__device__ __forceinline__ ushort8v pack8(float4 a, float4 b) {
  ushort8v v;
  v[0] = f2b(a.x); v[1] = f2b(a.y); v[2] = f2b(a.z); v[3] = f2b(a.w);
  v[4] = f2b(b.x); v[5] = f2b(b.y); v[6] = f2b(b.z); v[7] = f2b(b.w);
  return v;
}
__device__ __forceinline__ f32x4 mfma16(ushort8v a, ushort8v b, f32x4 c) {
  return __builtin_amdgcn_mfma_f32_16x16x32_bf16(
      __builtin_bit_cast(bf16x8, a), __builtin_bit_cast(bf16x8, b), c, 0, 0, 0);
}
__device__ __forceinline__ float sigm(float x) { return 1.f / (1.f + __expf(-x)); }
__device__ __forceinline__ float tanh_f(float x) {
  float e = __expf(2.f * x);
  return 1.f - 2.f / (e + 1.f);
}

// ---------------------------------------------------------------------------
// Kernel 1: bidirectional LSTM, 1 wave/WG. grid = 32 x 64 thr.
// ---------------------------------------------------------------------------
__global__ __launch_bounds__(64) void lstm_kernel(
    const float* __restrict__ x,
    const float* __restrict__ Wih0, const float* __restrict__ Whh0,
    const float* __restrict__ bih0, const float* __restrict__ bhh0,
    const float* __restrict__ Wih1, const float* __restrict__ Whh1,
    const float* __restrict__ bih1, const float* __restrict__ bhh1,
    u32* __restrict__ hbuf,   // [128][2][16][128] u32 (poisoned 0xFF)
    u32* __restrict__ tb32)   // [16][128][512] bf16 as u32 pairs
{
  const int ln = threadIdx.x;          // 0..63
  const int bx = blockIdx.x;
  const int d = bx >> 4, q = bx & 15;
  const float* Wih = d ? Wih1 : Wih0;
  const float* Whh = d ? Whh1 : Whh0;
  const float* bih = d ? bih1 : bih0;
  const float* bhh = d ? bhh1 : bhh0;

  __shared__ u16 whh_s[64][264];  // row stride 528B = 33*16 (aligned, 2-way ok)
  __shared__ u16 wih_s[64][72];   // row stride 144B = 9*16

  const int i15 = ln & 15;   // B-col n / batch m / h-col, context-dependent
  const int quad = ln >> 4;

  // ---- stage weights f32->bf16 into wave-private LDS (once) ----
  {
    int grow = ((ln >> 4) << 8) + q * 16 + (ln & 15);  // gate (ln>>4), row i
    const float4* src = (const float4*)(Whh + grow * 256);
#pragma unroll 4
    for (int c = 0; c < 32; c++)
      *(ushort8v*)&whh_s[ln][c * 8] = pack8(src[2 * c], src[2 * c + 1]);
    const float4* s2 = (const float4*)(Wih + grow * 64);
#pragma unroll
    for (int c = 0; c < 8; c++)
      *(ushort8v*)&wih_s[ln][c * 8] = pack8(s2[2 * c], s2[2 * c + 1]);
  }
  float bias4[4];
#pragma unroll
  for (int g = 0; g < 4; g++) {
    int grow = (g << 8) + q * 16 + i15;
    bias4[g] = bih[grow] + bhh[grow];
  }
  __syncthreads();

  float c_r[4] = {0.f, 0.f, 0.f, 0.f};  // cell for (batch quad*4+r, col i15)

  for (int t = 0; t < 128; t++) {
    const int pos = d ? (127 - t) : t;

    // x A-frags: batch m=i15, cols kt*32+quad*8..+7 (issue early, overlaps poll)
    const float4* xp = (const float4*)(x + (i15 * 128 + pos) * 64);
    float4 xa0 = xp[quad * 2], xa1 = xp[quad * 2 + 1];
    float4 xb0 = xp[8 + quad * 2], xb1 = xp[9 + quad * 2];

    // poll h(t): 8 dwordx4 = the 8 ktile A-frags for batch m=i15
    uint4v p0, p1, p2, p3, p4, p5, p6, p7;
    if (t > 0) {
      const u32* hw = hbuf + ((t * 2 + d) << 11) + (i15 << 7) + (quad << 2);
      for (;;) {
        asm volatile(
            "global_load_dwordx4 %0, %8, off sc1\n\t"
            "global_load_dwordx4 %1, %9, off sc1\n\t"
            "global_load_dwordx4 %2, %10, off sc1\n\t"
            "global_load_dwordx4 %3, %11, off sc1\n\t"
            "global_load_dwordx4 %4, %12, off sc1\n\t"
            "global_load_dwordx4 %5, %13, off sc1\n\t"
            "global_load_dwordx4 %6, %14, off sc1\n\t"
            "global_load_dwordx4 %7, %15, off sc1\n\t"
            "s_waitcnt vmcnt(0)"
            : "=v"(p0), "=v"(p1), "=v"(p2), "=v"(p3),
              "=v"(p4), "=v"(p5), "=v"(p6), "=v"(p7)
            : "v"(hw), "v"(hw + 16), "v"(hw + 32), "v"(hw + 48),
              "v"(hw + 64), "v"(hw + 80), "v"(hw + 96), "v"(hw + 112)
            : "memory");
        bool ok = (p0.x != POISON) & (p0.y != POISON) & (p0.z != POISON) & (p0.w != POISON) &
                  (p1.x != POISON) & (p1.y != POISON) & (p1.z != POISON) & (p1.w != POISON) &
                  (p2.x != POISON) & (p2.y != POISON) & (p2.z != POISON) & (p2.w != POISON) &
                  (p3.x != POISON) & (p3.y != POISON) & (p3.z != POISON) & (p3.w != POISON) &
                  (p4.x != POISON) & (p4.y != POISON) & (p4.z != POISON) & (p4.w != POISON) &
                  (p5.x != POISON) & (p5.y != POISON) & (p5.z != POISON) & (p5.w != POISON) &
                  (p6.x != POISON) & (p6.y != POISON) & (p6.z != POISON) & (p6.w != POISON) &
                  (p7.x != POISON) & (p7.y != POISON) & (p7.z != POISON) & (p7.w != POISON);
        if (__ballot(ok) == ~0ull) break;
      }
    }

    // MFMA: acc[n] = gate n (N-tile n), M=batch, all in this wave
    f32x4 acc[4];
#pragma unroll
    for (int n = 0; n < 4; n++) acc[n] = (f32x4){0.f, 0.f, 0.f, 0.f};
    ushort8v xf0 = pack8(xa0, xa1), xf1 = pack8(xb0, xb1);
#pragma unroll
    for (int n = 0; n < 4; n++) {
      acc[n] = mfma16(xf0, *(const ushort8v*)&wih_s[n * 16 + i15][quad * 8], acc[n]);
      acc[n] = mfma16(xf1, *(const ushort8v*)&wih_s[n * 16 + i15][32 + quad * 8], acc[n]);
    }
    if (t > 0) {
      ushort8v af[8] = {
          __builtin_bit_cast(ushort8v, p0), __builtin_bit_cast(ushort8v, p1),
          __builtin_bit_cast(ushort8v, p2), __builtin_bit_cast(ushort8v, p3),
          __builtin_bit_cast(ushort8v, p4), __builtin_bit_cast(ushort8v, p5),
          __builtin_bit_cast(ushort8v, p6), __builtin_bit_cast(ushort8v, p7)};
#pragma unroll
      for (int kt = 0; kt < 8; kt++)
#pragma unroll
        for (int n = 0; n < 4; n++)
          acc[n] = mfma16(af[kt],
                          *(const ushort8v*)&whh_s[n * 16 + i15][kt * 32 + quad * 8],
                          acc[n]);
    }

    // gates lane-local: acc[g][r] = z_gate_g(batch quad*4+r, col i15)
    u32 word[4];
#pragma unroll
    for (int r = 0; r < 4; r++) {
      float zi = acc[0][r] + bias4[0];
      float zf = acc[1][r] + bias4[1];
      float zg = acc[2][r] + bias4[2];
      float zo = acc[3][r] + bias4[3];
      float si = sigm(zi), sf = sigm(zf), so = sigm(zo);
      float tg = tanh_f(zg);
      c_r[r] = sf * c_r[r] + si * tg;
      float hv = so * tanh_f(c_r[r]);
      u32 m = (u32)f2b(hv);
      u32 o = (u32)__shfl_xor((int)m, 1);  // partner col i15^1
      word[r] = m | (o << 16);             // valid on even i15
    }
    if (!(i15 & 1)) {
      const int cw = q * 8 + (i15 >> 1);
      if (t < 127) {
        u32* hb = hbuf + (((t + 1) * 2 + d) << 11) + cw;
#pragma unroll
        for (int r = 0; r < 4; r++)
          __hip_atomic_store(hb + (quad * 4 + r) * 128, word[r],
                             __ATOMIC_RELAXED, __HIP_MEMORY_SCOPE_AGENT);
      }
#pragma unroll
      for (int r = 0; r < 4; r++)
        tb32[((quad * 4 + r) * 128 + pos) * 256 + d * 128 + cw] = word[r];
    }
  }
}

// ---------------------------------------------------------------------------
// Kernel 1b: convert Wq/Wk/Wv f32 -> bf16 once. grid (128, 3) x 256.
// ---------------------------------------------------------------------------
__global__ __launch_bounds__(256) void wcvt_kernel(
    const float* __restrict__ Wq, const float* __restrict__ Wk,
    const float* __restrict__ Wv,
    u16* __restrict__ oq, u16* __restrict__ ok2, u16* __restrict__ ov)
{
  const float* s = (blockIdx.y == 0) ? Wq : ((blockIdx.y == 1) ? Wk : Wv);
  u16* o = (blockIdx.y == 0) ? oq : ((blockIdx.y == 1) ? ok2 : ov);
  int idx = blockIdx.x * 256 + threadIdx.x;  // 32768 threads x 8 floats
  const float4* sp = (const float4*)s + idx * 2;
  *(ushort8v*)(o + idx * 8) = pack8(sp[0], sp[1]);
}

// ---------------------------------------------------------------------------
// Kernel 2: QKV projection. out = t @ W^T + bias, M=2048 N=512 K=512, bf16 W.
// grid = (32 Mtiles, 8 Ntiles, 3 which).
// ---------------------------------------------------------------------------
__global__ __launch_bounds__(256) void qkv_kernel(
    const u16* __restrict__ tb,
    const u16* __restrict__ Wqb, const float* __restrict__ bq,
    const u16* __restrict__ Wkb, const float* __restrict__ bk,
    const u16* __restrict__ Wvb, const float* __restrict__ bv,
    u16* __restrict__ Qb, u16* __restrict__ Kb, u16* __restrict__ Vb)
{
  const int tid = threadIdx.x;
  const int bxm = blockIdx.x, byn = blockIdx.y, bz = blockIdx.z;
  const u16* W = (bz == 0) ? Wqb : ((bz == 1) ? Wkb : Wvb);
  const float* bias = (bz == 0) ? bq : ((bz == 1) ? bk : bv);
  u16* outp = (bz == 0) ? Qb : ((bz == 1) ? Kb : Vb);

  __shared__ u16 a_s[64][40];
  __shared__ u16 b_s[64][40];
  const int w = tid >> 6, ln = tid & 63, col16 = ln & 15, quad = ln >> 4;

  f32x4 acc[4];
#pragma unroll
  for (int n = 0; n < 4; n++) acc[n] = (f32x4){0.f, 0.f, 0.f, 0.f};

  for (int kt = 0; kt < 16; kt++) {
    int r = tid >> 2, seg = tid & 3;
    *(ushort8v*)&a_s[r][seg * 8] =
        *(const ushort8v*)(tb + (bxm * 64 + r) * 512 + kt * 32 + seg * 8);
    *(ushort8v*)&b_s[r][seg * 8] =
        *(const ushort8v*)(W + (byn * 64 + r) * 512 + kt * 32 + seg * 8);
    __syncthreads();
    ushort8v av = *(const ushort8v*)&a_s[w * 16 + col16][quad * 8];
#pragma unroll
    for (int n = 0; n < 4; n++) {
      ushort8v bvv = *(const ushort8v*)&b_s[n * 16 + col16][quad * 8];
      acc[n] = mfma16(av, bvv, acc[n]);
    }
    __syncthreads();
  }
#pragma unroll
  for (int n = 0; n < 4; n++) {
    float bs = bias[byn * 64 + n * 16 + col16];
#pragma unroll
    for (int reg = 0; reg < 4; reg++) {
      int row = bxm * 64 + w * 16 + quad * 4 + reg;
      outp[row * 512 + byn * 64 + n * 16 + col16] = f2b(acc[n][reg] + bs);
    }
  }
}

// ---------------------------------------------------------------------------
// Kernel 3: scores + softmax -> attn (d_out, f32). grid = (16 b, 4 h, 2 qhalf).
// ---------------------------------------------------------------------------
__global__ __launch_bounds__(256) void attn_kernel(
    const u16* __restrict__ Qb, const u16* __restrict__ Kb,
    float* __restrict__ attn_out)
{
  const int b = blockIdx.x, h = blockIdx.y, half = blockIdx.z;
  const int tid = threadIdx.x;
  __shared__ __align__(16) char smem[52224];
  u16 (*q_s)[136] = (u16(*)[136])smem;
  u16 (*k_s)[136] = (u16(*)[136])(smem + 17408);
  float (*sc)[132] = (float(*)[132])smem;  // reused after MFMA

  const int w = tid >> 6, ln = tid & 63, col16 = ln & 15, quad = ln >> 4;
  {
    int r = tid >> 2, seg = tid & 3;
    const u16* src = Qb + (b * 128 + half * 64 + r) * 512 + h * 128 + seg * 32;
#pragma unroll
    for (int i = 0; i < 4; i++)
      *(ushort8v*)&q_s[r][seg * 32 + i * 8] = *(const ushort8v*)(src + i * 8);
    int r2 = tid >> 1, sg = tid & 1;
    const u16* src2 = Kb + (b * 128 + r2) * 512 + h * 128 + sg * 64;
#pragma unroll
    for (int i = 0; i < 8; i++)
      *(ushort8v*)&k_s[r2][sg * 64 + i * 8] = *(const ushort8v*)(src2 + i * 8);
  }
  __syncthreads();

  f32x4 acc[8];
#pragma unroll
  for (int n = 0; n < 8; n++) acc[n] = (f32x4){0.f, 0.f, 0.f, 0.f};
#pragma unroll
  for (int kd = 0; kd < 4; kd++) {
    ushort8v av = *(const ushort8v*)&q_s[w * 16 + col16][kd * 32 + quad * 8];
#pragma unroll
    for (int n = 0; n < 8; n++) {
      ushort8v bvv = *(const ushort8v*)&k_s[n * 16 + col16][kd * 32 + quad * 8];
      acc[n] = mfma16(av, bvv, acc[n]);
    }
  }
  __syncthreads();
  const float scale = 0.08838834764831845f;  // 1/sqrt(128)
#pragma unroll
  for (int n = 0; n < 8; n++)
#pragma unroll
    for (int reg = 0; reg < 4; reg++)
      sc[w * 16 + quad * 4 + reg][n * 16 + col16] = acc[n][reg] * scale;
  __syncthreads();

  const int row = tid >> 2, p = tid & 3;
  float m = -1e30f;
  for (int c0 = 0; c0 < 32; c0++) m = fmaxf(m, sc[row][p * 32 + c0]);
  m = fmaxf(m, __shfl_xor(m, 1));
  m = fmaxf(m, __shfl_xor(m, 2));
  float s = 0.f;
  for (int c0 = 0; c0 < 32; c0++) {
    float e = __expf(sc[row][p * 32 + c0] - m);
    sc[row][p * 32 + c0] = e;
    s += e;
  }
  s += __shfl_xor(s, 1);
  s += __shfl_xor(s, 2);
  float inv = 1.f / s;
  float* orow = attn_out + ((b * 4 + h) * 128 + half * 64 + row) * 128 + p * 32;
  for (int c0 = 0; c0 < 32; c0++) orow[c0] = sc[row][p * 32 + c0] * inv;
}

// ---------------------------------------------------------------------------
// Kernel 4: ao (q=127), last = ao@Wo^T+bo, collapsed GAT, fusion+LN+ReLU.
// grid = 16 (batch), 256 threads.
// ---------------------------------------------------------------------------
__global__ __launch_bounds__(256) void tail_kernel(
    const float* __restrict__ attn, const u16* __restrict__ Vb,
    const float* __restrict__ Wo, const float* __restrict__ bo,
    const float* __restrict__ W1, const float* __restrict__ b1,
    const float* __restrict__ g1, const float* __restrict__ be1,
    const float* __restrict__ W2, const float* __restrict__ pb2,
    const float* __restrict__ g2, const float* __restrict__ be2,
    const float* __restrict__ Wf, const float* __restrict__ bfv,
    const float* __restrict__ ln_g, const float* __restrict__ ln_b,
    float* __restrict__ dout)
{
  const int b = blockIdx.x, tid = threadIdx.x;
  __shared__ float arow[4][128];
  __shared__ float ao_s[512];
  __shared__ float last_s[512];
  __shared__ float h_s2[256];
  __shared__ float red_s[4];

#pragma unroll
  for (int e = 0; e < 2; e++) {
    int idx = tid + e * 256;
    int h = idx >> 7, k = idx & 127;
    arow[h][k] = attn[((b * 4 + h) * 128 + 127) * 128 + k];
  }
  __syncthreads();
#pragma unroll
  for (int pass = 0; pass < 2; pass++) {
    int d2 = tid + pass * 256;
    int hh = d2 >> 7;
    float acc = 0.f;
    for (int k = 0; k < 128; k++)
      acc += arow[hh][k] * b2f(Vb[(b * 128 + k) * 512 + d2]);
    ao_s[d2] = acc;
  }
  __syncthreads();
#pragma unroll
  for (int pass = 0; pass < 2; pass++) {
    int j = tid + pass * 256;
    float acc = bo[j];
    const float4* Wo4 = (const float4*)(Wo + j * 512);
    for (int k4 = 0; k4 < 128; k4++) {
      float4 wv = Wo4[k4];
      acc += ao_s[k4 * 4 + 0] * wv.x + ao_s[k4 * 4 + 1] * wv.y +
             ao_s[k4 * 4 + 2] * wv.z + ao_s[k4 * 4 + 3] * wv.w;
    }
    last_s[j] = acc;
  }
  __syncthreads();

  const int j = tid;
  float acc = 0.f;
  for (int k = 0; k < 512; k++) acc += last_s[k] * W1[k * 256 + j];
  float u = (acc + b1[j]) * BN_INV_F * g1[j] + be1[j];
  float h1 = u > 0.f ? u : expm1f(u);
  h_s2[j] = h1;
  __syncthreads();

  float acc2 = 0.f;
  for (int k = 0; k < 256; k++) acc2 += h_s2[k] * W2[k * 256 + j];
  float u2 = (acc2 + pb2[j]) * BN_INV_F * g2[j] + be2[j];
  float sp = u2 > 0.f ? u2 : expm1f(u2);
  __syncthreads();
  h_s2[j] = sp;
  __syncthreads();

  float f = bfv[j];
  const float4* Wf4 = (const float4*)(Wf + j * 768);
  for (int k4 = 0; k4 < 128; k4++) {
    float4 wv = Wf4[k4];
    f += last_s[k4 * 4 + 0] * wv.x + last_s[k4 * 4 + 1] * wv.y +
         last_s[k4 * 4 + 2] * wv.z + last_s[k4 * 4 + 3] * wv.w;
  }
  for (int k4 = 0; k4 < 64; k4++) {
    float4 wv = Wf4[128 + k4];
    f += h_s2[k4 * 4 + 0] * wv.x + h_s2[k4 * 4 + 1] * wv.y +
         h_s2[k4 * 4 + 2] * wv.z + h_s2[k4 * 4 + 3] * wv.w;
  }

  float v = f;
#pragma unroll
  for (int o = 32; o > 0; o >>= 1) v += __shfl_xor(v, o);
  if ((tid & 63) == 0) red_s[tid >> 6] = v;
  __syncthreads();
  float mu = (red_s[0] + red_s[1] + red_s[2] + red_s[3]) * (1.f / 256.f);
  float dv = f - mu;
  float vv = dv * dv;
#pragma unroll
  for (int o = 32; o > 0; o >>= 1) vv += __shfl_xor(vv, o);
  __syncthreads();
  if ((tid & 63) == 0) red_s[tid >> 6] = vv;
  __syncthreads();
  float var = (red_s[0] + red_s[1] + red_s[2] + red_s[3]) * (1.f / 256.f);
  float y = dv * rsqrtf(var + 1e-5f) * ln_g[j] + ln_b[j];
  dout[b * 256 + j] = fmaxf(y, 0.f);
}

// ---------------------------------------------------------------------------
// ws layout (bytes):
//   0         hbuf  [128][2][16][128] u32  2097152  (memset 0xFF each call)
//   2097152   tb    [16][128][512] bf16    2097152
//   4194304   Q     [2048][512] bf16       2097152
//   6291456   K     [2048][512] bf16       2097152
//   8388608   V     [2048][512] bf16       2097152
//   10485760  Wqb   [512][512]  bf16        524288
//   11010048  Wkb                           524288
//   11534336  Wvb                           524288  -> total 12058624 bytes
// ---------------------------------------------------------------------------
extern "C" void kernel_launch(void* const* d_in, const int* in_sizes, int n_in,
                              void* d_out, int out_size, void* d_ws, size_t ws_size,
                              hipStream_t stream) {
  (void)in_sizes; (void)n_in; (void)out_size; (void)ws_size;
  const float* x     = (const float*)d_in[0];
  const float* Wih_f = (const float*)d_in[2];
  const float* Whh_f = (const float*)d_in[3];
  const float* bih_f = (const float*)d_in[4];
  const float* bhh_f = (const float*)d_in[5];
  const float* Wih_b = (const float*)d_in[6];
  const float* Whh_b = (const float*)d_in[7];
  const float* bih_b = (const float*)d_in[8];
  const float* bhh_b = (const float*)d_in[9];
  const float* Wq = (const float*)d_in[10]; const float* bq = (const float*)d_in[11];
  const float* Wk = (const float*)d_in[12]; const float* bk = (const float*)d_in[13];
  const float* Wv = (const float*)d_in[14]; const float* bv = (const float*)d_in[15];
  const float* Wo = (const float*)d_in[16]; const float* bo = (const float*)d_in[17];
  const float* W1 = (const float*)d_in[18];
  const float* b1 = (const float*)d_in[21];
  const float* g1 = (const float*)d_in[22]; const float* be1 = (const float*)d_in[23];
  const float* W2 = (const float*)d_in[24];
  const float* pb2 = (const float*)d_in[27];
  const float* g2 = (const float*)d_in[28]; const float* be2 = (const float*)d_in[29];
  const float* Wf = (const float*)d_in[30]; const float* bfv = (const float*)d_in[31];
  const float* ln_g = (const float*)d_in[32]; const float* ln_b = (const float*)d_in[33];

  float* dout = (float*)d_out;
  char* ws = (char*)d_ws;
  u32* hbuf = (u32*)(ws + 0);
  u16* tb   = (u16*)(ws + 2097152);
  u16* Qb   = (u16*)(ws + 4194304);
  u16* Kb   = (u16*)(ws + 6291456);
  u16* Vb   = (u16*)(ws + 8388608);
  u16* Wqb  = (u16*)(ws + 10485760);
  u16* Wkb  = (u16*)(ws + 11010048);
  u16* Wvb  = (u16*)(ws + 11534336);

  (void)hipMemsetAsync(ws, 0xFF, 2097152, stream);  // poison hbuf ring
  lstm_kernel<<<32, 64, 0, stream>>>(x, Wih_f, Whh_f, bih_f, bhh_f,
                                     Wih_b, Whh_b, bih_b, bhh_b,
                                     hbuf, (u32*)tb);
  wcvt_kernel<<<dim3(128, 3), 256, 0, stream>>>(Wq, Wk, Wv, Wqb, Wkb, Wvb);
  qkv_kernel<<<dim3(32, 8, 3), 256, 0, stream>>>(tb, Wqb, bq, Wkb, bk, Wvb, bv,
                                                 Qb, Kb, Vb);
  attn_kernel<<<dim3(16, 4, 2), 256, 0, stream>>>(Qb, Kb, dout + 4096);
  tail_kernel<<<16, 256, 0, stream>>>(dout + 4096, Vb, Wo, bo,
                                      W1, b1, g1, be1, W2, pb2, g2, be2,
                                      Wf, bfv, ln_g, ln_b, dout);
}

// Round 7
// 457.015 us; speedup vs baseline: 1.3671x; 1.3671x over previous
//
#include <hip/hip_runtime.h>

// ---------------------------------------------------------------------------
// SpatioTemporalBlock: biLSTM -> temporal MHA -> (collapsed) GAT -> fusion
// B=16 S=128 F=64 H=256 HEADS=4 DH=64 AH=128 D2=512
// FP32 inputs/outputs; MFMA operands converted f32->bf16 at staging.
// GAT collapses: broadcast node features => uniform alpha => dense layers.
// V eliminated: softmax rows sum to 1 => ao = (attn127 @ t) @ Wv^T + bv.
// LSTM (R5 structure, 4 waves/WG): poison-word sync, hbuf write-once ring
// [128][2][16][128] u32 (memset 0xFF); publish = relaxed agent u32 stores,
// poll = coalesced sc1 dwordx4 loads until != 0xFFFFFFFF (h bounded by
// sigmoid*tanh => NaN pattern impossible).
// ---------------------------------------------------------------------------

typedef unsigned short u16;
typedef unsigned int u32;
typedef __bf16 bf16x8 __attribute__((ext_vector_type(8)));
typedef float f32x4 __attribute__((ext_vector_type(4)));
typedef unsigned short ushort8v __attribute__((ext_vector_type(8)));
typedef unsigned int uint4v __attribute__((ext_vector_type(4)));

#define BN_INV_F 0.9999950000374997f
#define POISON 0xFFFFFFFFu

__device__ __forceinline__ float b2f(u16 u) {
  union { float f; unsigned int i; } v;
  v.i = ((unsigned int)u) << 16;
  return v.f;
}
__device__ __forceinline__ u16 f2b(float f) {
  union { float f; unsigned int i; } v;
  v.f = f;
  unsigned int x = v.i;
  unsigned int r = (x + 0x7FFFu + ((x >> 16) & 1u)) >> 16;
  return (u16)r;
}
__device__ __forceinline__ ushort8v pack8(float4 a, float4 b) {
  ushort8v v;
  v[0] = f2b(a.x); v[1] = f2b(a.y); v[2] = f2b(a.z); v[3] = f2b(a.w);
  v[4] = f2b(b.x); v[5] = f2b(b.y); v[6] = f2b(b.z); v[7] = f2b(b.w);
  return v;
}
__device__ __forceinline__ f32x4 mfma16(ushort8v a, ushort8v b, f32x4 c) {
  return __builtin_amdgcn_mfma_f32_16x16x32_bf16(
      __builtin_bit_cast(bf16x8, a), __builtin_bit_cast(bf16x8, b), c, 0, 0, 0);
}
__device__ __forceinline__ float sigm(float x) { return 1.f / (1.f + __expf(-x)); }
__device__ __forceinline__ float tanh_f(float x) {
  float e = __expf(2.f * x);
  return 1.f - 2.f / (e + 1.f);
}

// ---------------------------------------------------------------------------
// Kernel 1: bidirectional LSTM (R5 structure) + fused Wq/Wk bf16 conversion.
// grid = 64 x 256: blocks 0..31 LSTM (dir=bx>>4, chunk q=bx&15);
// blocks 32..63 convert Wq (32..47) / Wk (48..63) f32->bf16 on idle CUs.
// ---------------------------------------------------------------------------
__global__ __launch_bounds__(256) void lstm_kernel(
    const float* __restrict__ x,
    const float* __restrict__ Wih0, const float* __restrict__ Whh0,
    const float* __restrict__ bih0, const float* __restrict__ bhh0,
    const float* __restrict__ Wih1, const float* __restrict__ Whh1,
    const float* __restrict__ bih1, const float* __restrict__ bhh1,
    const float* __restrict__ Wq, const float* __restrict__ Wk,
    u16* __restrict__ Wqb, u16* __restrict__ Wkb,
    u32* __restrict__ hbuf,   // [128][2][16][128] u32 (poisoned 0xFF)
    u16* __restrict__ tb)     // [16][128][512] bf16
{
  const int tid = threadIdx.x;
  const int bx = blockIdx.x;

  if (bx >= 32) {  // ---- weight conversion side-blocks ----
    const float* s = (bx < 48) ? Wq : Wk;
    u16* o = (bx < 48) ? Wqb : Wkb;
    int idx = ((bx & 15) << 8) + tid;  // 0..4095
#pragma unroll
    for (int i = 0; i < 8; i++) {
      int e8 = i * 4096 + idx;  // 8-float chunk id, 0..32767
      const float4* sp = (const float4*)s + e8 * 2;
      *(ushort8v*)(o + e8 * 8) = pack8(sp[0], sp[1]);
    }
    return;
  }

  const int d = bx >> 4;
  const int q = bx & 15;
  const float* Wih = d ? Wih1 : Wih0;
  const float* Whh = d ? Whh1 : Whh0;
  const float* bih = d ? bih1 : bih0;
  const float* bhh = d ? bhh1 : bhh0;

  __shared__ u16 whh_s[64][264];
  __shared__ u16 wih_s[64][72];
  __shared__ u16 h_s[16][264];
  __shared__ u16 x_s[16][72];
  __shared__ float z_s[4][16][17];
  __shared__ float bias_s[64];

  {
    int r = tid >> 2, seg = tid & 3;
    int grow = ((r >> 4) << 8) + q * 16 + (r & 15);
    const float4* src = (const float4*)(Whh + grow * 256 + seg * 64);
#pragma unroll
    for (int i = 0; i < 8; i++)
      *(ushort8v*)&whh_s[r][seg * 64 + i * 8] = pack8(src[2 * i], src[2 * i + 1]);
    const float4* src2 = (const float4*)(Wih + grow * 64 + seg * 16);
    *(ushort8v*)&wih_s[r][seg * 16] = pack8(src2[0], src2[1]);
    *(ushort8v*)&wih_s[r][seg * 16 + 8] = pack8(src2[2], src2[3]);
  }
  if (tid < 64) {
    int grow = ((tid >> 4) << 8) + q * 16 + (tid & 15);
    bias_s[tid] = bih[grow] + bhh[grow];
  }

  const int w = tid >> 6;
  const int ln = tid & 63;
  const int col16 = ln & 15;
  const int quad = ln >> 4;
  const int eb = tid >> 4;  // elementwise: batch
  const int ec = tid & 15;  // elementwise: h-col within chunk
  float c_reg = 0.f;

  for (int t = 0; t < 128; t++) {
    const int pos = d ? (127 - t) : t;
    // stage x(pos) -> bf16 LDS (plain cached loads)
    {
      int b_ = tid >> 4;
      int f0 = (tid & 15) * 4;
      float4 xv = *(const float4*)(x + (b_ * 128 + pos) * 64 + f0);
      x_s[b_][f0 + 0] = f2b(xv.x);
      x_s[b_][f0 + 1] = f2b(xv.y);
      x_s[b_][f0 + 2] = f2b(xv.z);
      x_s[b_][f0 + 3] = f2b(xv.w);
    }
    if (t > 0) {
      // poll full h(t): 8 u32 words per thread via 2 coalesced sc1 x4 loads
      const u32* hw = hbuf + (t * 2 + d) * 2048 + tid * 8;
      uint4v a, b;
      for (;;) {
        asm volatile(
            "global_load_dwordx4 %0, %2, off sc1\n\t"
            "global_load_dwordx4 %1, %3, off sc1\n\t"
            "s_waitcnt vmcnt(0)"
            : "=v"(a), "=v"(b)
            : "v"(hw), "v"(hw + 4)
            : "memory");
        bool ok = (a.x != POISON) & (a.y != POISON) & (a.z != POISON) &
                  (a.w != POISON) & (b.x != POISON) & (b.y != POISON) &
                  (b.z != POISON) & (b.w != POISON);
        if (ok) break;
      }
      int b_ = tid >> 4, c0 = (tid & 15) * 16;
      *(u32*)&h_s[b_][c0 + 0] = a.x;
      *(u32*)&h_s[b_][c0 + 2] = a.y;
      *(u32*)&h_s[b_][c0 + 4] = a.z;
      *(u32*)&h_s[b_][c0 + 6] = a.w;
      *(u32*)&h_s[b_][c0 + 8] = b.x;
      *(u32*)&h_s[b_][c0 + 10] = b.y;
      *(u32*)&h_s[b_][c0 + 12] = b.z;
      *(u32*)&h_s[b_][c0 + 14] = b.w;
    }
    __syncthreads();

    f32x4 acc = {0.f, 0.f, 0.f, 0.f};
#pragma unroll
    for (int kt = 0; kt < 2; kt++) {
      ushort8v av = *(const ushort8v*)&x_s[col16][kt * 32 + quad * 8];
      ushort8v bv = *(const ushort8v*)&wih_s[w * 16 + col16][kt * 32 + quad * 8];
      acc = mfma16(av, bv, acc);
    }
    if (t > 0) {
#pragma unroll
      for (int kt = 0; kt < 8; kt++) {
        ushort8v av = *(const ushort8v*)&h_s[col16][kt * 32 + quad * 8];
        ushort8v bv = *(const ushort8v*)&whh_s[w * 16 + col16][kt * 32 + quad * 8];
        acc = mfma16(av, bv, acc);
      }
    }
#pragma unroll
    for (int reg = 0; reg < 4; reg++)
      z_s[w][quad * 4 + reg][col16] = acc[reg];
    __syncthreads();

    // gates: torch order i, f, g, o (f32)
    float zi = z_s[0][eb][ec] + bias_s[ec];
    float zf = z_s[1][eb][ec] + bias_s[16 + ec];
    float zg = z_s[2][eb][ec] + bias_s[32 + ec];
    float zo = z_s[3][eb][ec] + bias_s[48 + ec];
    float si = sigm(zi), sf = sigm(zf), so = sigm(zo);
    float tg = tanh_f(zg);
    c_reg = sf * c_reg + si * tg;
    float hv = so * tanh_f(c_reg);
    u32 my = (u32)f2b(hv);
    u32 hi = __shfl_down((int)my, 1);  // partner col (ec+1), same wave
    if (!(ec & 1)) {
      u32 word = my | (hi << 16);
      *(u32*)&tb[(eb * 128 + pos) * 512 + d * 256 + q * 16 + ec] = word;
      if (t < 127) {
        u32* dst = hbuf + ((t + 1) * 2 + d) * 2048 + eb * 128 + (q * 16 + ec) / 2;
        __hip_atomic_store(dst, word, __ATOMIC_RELAXED,
                           __HIP_MEMORY_SCOPE_AGENT);
      }
    }
  }
}

// ---------------------------------------------------------------------------
// Kernel 2: Q,K projection. out = t @ W^T + bias, M=2048 N=512 K=512, bf16 W.
// grid = (32 Mtiles, 8 Ntiles, 2 which).
// ---------------------------------------------------------------------------
__global__ __launch_bounds__(256) void qk_kernel(
    const u16* __restrict__ tb,
    const u16* __restrict__ Wqb, const float* __restrict__ bq,
    const u16* __restrict__ Wkb, const float* __restrict__ bk,
    u16* __restrict__ Qb, u16* __restrict__ Kb)
{
  const int tid = threadIdx.x;
  const int bxm = blockIdx.x, byn = blockIdx.y, bz = blockIdx.z;
  const u16* W = (bz == 0) ? Wqb : Wkb;
  const float* bias = (bz == 0) ? bq : bk;
  u16* outp = (bz == 0) ? Qb : Kb;

  __shared__ u16 a_s[64][40];
  __shared__ u16 b_s[64][40];
  const int w = tid >> 6, ln = tid & 63, col16 = ln & 15, quad = ln >> 4;

  f32x4 acc[4];
#pragma unroll
  for (int n = 0; n < 4; n++) acc[n] = (f32x4){0.f, 0.f, 0.f, 0.f};

  for (int kt = 0; kt < 16; kt++) {
    int r = tid >> 2, seg = tid & 3;
    *(ushort8v*)&a_s[r][seg * 8] =
        *(const ushort8v*)(tb + (bxm * 64 + r) * 512 + kt * 32 + seg * 8);
    *(ushort8v*)&b_s[r][seg * 8] =
        *(const ushort8v*)(W + (byn * 64 + r) * 512 + kt * 32 + seg * 8);
    __syncthreads();
    ushort8v av = *(const ushort8v*)&a_s[w * 16 + col16][quad * 8];
#pragma unroll
    for (int n = 0; n < 4; n++) {
      ushort8v bvv = *(const ushort8v*)&b_s[n * 16 + col16][quad * 8];
      acc[n] = mfma16(av, bvv, acc[n]);
    }
    __syncthreads();
  }
#pragma unroll
  for (int n = 0; n < 4; n++) {
    float bs = bias[byn * 64 + n * 16 + col16];
#pragma unroll
    for (int reg = 0; reg < 4; reg++) {
      int row = bxm * 64 + w * 16 + quad * 4 + reg;
      outp[row * 512 + byn * 64 + n * 16 + col16] = f2b(acc[n][reg] + bs);
    }
  }
}

// ---------------------------------------------------------------------------
// Kernel 3: scores + softmax -> attn (d_out, f32). grid = (16 b, 4 h, 2 qhalf).
// ---------------------------------------------------------------------------
__global__ __launch_bounds__(256) void attn_kernel(
    const u16* __restrict__ Qb, const u16* __restrict__ Kb,
    float* __restrict__ attn_out)
{
  const int b = blockIdx.x, h = blockIdx.y, half = blockIdx.z;
  const int tid = threadIdx.x;
  __shared__ __align__(16) char smem[52224];
  u16 (*q_s)[136] = (u16(*)[136])smem;
  u16 (*k_s)[136] = (u16(*)[136])(smem + 17408);
  float (*sc)[132] = (float(*)[132])smem;  // reused after MFMA

  const int w = tid >> 6, ln = tid & 63, col16 = ln & 15, quad = ln >> 4;
  {
    int r = tid >> 2, seg = tid & 3;
    const u16* src = Qb + (b * 128 + half * 64 + r) * 512 + h * 128 + seg * 32;
#pragma unroll
    for (int i = 0; i < 4; i++)
      *(ushort8v*)&q_s[r][seg * 32 + i * 8] = *(const ushort8v*)(src + i * 8);
    int r2 = tid >> 1, sg = tid & 1;
    const u16* src2 = Kb + (b * 128 + r2) * 512 + h * 128 + sg * 64;
#pragma unroll
    for (int i = 0; i < 8; i++)
      *(ushort8v*)&k_s[r2][sg * 64 + i * 8] = *(const ushort8v*)(src2 + i * 8);
  }
  __syncthreads();

  f32x4 acc[8];
#pragma unroll
  for (int n = 0; n < 8; n++) acc[n] = (f32x4){0.f, 0.f, 0.f, 0.f};
#pragma unroll
  for (int kd = 0; kd < 4; kd++) {
    ushort8v av = *(const ushort8v*)&q_s[w * 16 + col16][kd * 32 + quad * 8];
#pragma unroll
    for (int n = 0; n < 8; n++) {
      ushort8v bvv = *(const ushort8v*)&k_s[n * 16 + col16][kd * 32 + quad * 8];
      acc[n] = mfma16(av, bvv, acc[n]);
    }
  }
  __syncthreads();
  const float scale = 0.08838834764831845f;  // 1/sqrt(128)
#pragma unroll
  for (int n = 0; n < 8; n++)
#pragma unroll
    for (int reg = 0; reg < 4; reg++)
      sc[w * 16 + quad * 4 + reg][n * 16 + col16] = acc[n][reg] * scale;
  __syncthreads();

  const int row = tid >> 2, p = tid & 3;
  float m = -1e30f;
  for (int c0 = 0; c0 < 32; c0++) m = fmaxf(m, sc[row][p * 32 + c0]);
  m = fmaxf(m, __shfl_xor(m, 1));
  m = fmaxf(m, __shfl_xor(m, 2));
  float s = 0.f;
  for (int c0 = 0; c0 < 32; c0++) {
    float e = __expf(sc[row][p * 32 + c0] - m);
    sc[row][p * 32 + c0] = e;
    s += e;
  }
  s += __shfl_xor(s, 1);
  s += __shfl_xor(s, 2);
  float inv = 1.f / s;
  float* orow = attn_out + ((b * 4 + h) * 128 + half * 64 + row) * 128 + p * 32;
  for (int c0 = 0; c0 < 32; c0++) orow[c0] = sc[row][p * 32 + c0] * inv;
}

// ---------------------------------------------------------------------------
// Kernel 4: tail. u = attn127 @ t_b (per head), ao = u @ Wv^T + bv (exact:
// softmax row sums to 1), last = ao @ Wo^T + bo, collapsed GAT, fusion + LN.
// grid = 16 (batch), 256 threads.
// ---------------------------------------------------------------------------
__global__ __launch_bounds__(256) void tail_kernel(
    const float* __restrict__ attn, const u16* __restrict__ tb,
    const float* __restrict__ Wv, const float* __restrict__ bv,
    const float* __restrict__ Wo, const float* __restrict__ bo,
    const float* __restrict__ W1, const float* __restrict__ b1,
    const float* __restrict__ g1, const float* __restrict__ be1,
    const float* __restrict__ W2, const float* __restrict__ pb2,
    const float* __restrict__ g2, const float* __restrict__ be2,
    const float* __restrict__ Wf, const float* __restrict__ bfv,
    const float* __restrict__ ln_g, const float* __restrict__ ln_b,
    float* __restrict__ dout)
{
  const int b = blockIdx.x, tid = threadIdx.x;
  __shared__ float arow[4][128];
  __shared__ float u_s[4][512];
  __shared__ float ao_s[512];
  __shared__ float last_s[512];
  __shared__ float h_s2[256];
  __shared__ float red_s[4];

  // ---- attn row 127, all 4 heads ----
#pragma unroll
  for (int e = 0; e < 2; e++) {
    int idx = tid + e * 256;
    int h = idx >> 7, k = idx & 127;
    arow[h][k] = attn[((b * 4 + h) * 128 + 127) * 128 + k];
  }
  __syncthreads();

  // ---- u[h][c] = sum_k arow[h][k] * t_b[k][c] ----
  {
    int h = tid >> 6, c0 = (tid & 63) * 8;
    float acc8[8] = {0.f};
    for (int k = 0; k < 128; k++) {
      float a = arow[h][k];
      ushort8v tv = *(const ushort8v*)(tb + (b * 128 + k) * 512 + c0);
#pragma unroll
      for (int i = 0; i < 8; i++) acc8[i] += a * b2f(tv[i]);
    }
#pragma unroll
    for (int i = 0; i < 8; i++) u_s[h][c0 + i] = acc8[i];
  }
  __syncthreads();

  // ---- ao[col] = bv[col] + u[h(col)] . Wv[col,:] ----
#pragma unroll
  for (int pass = 0; pass < 2; pass++) {
    int col = tid + pass * 256;
    int h = col >> 7;
    float acc = bv[col];
    const float4* Wv4 = (const float4*)(Wv + col * 512);
    for (int k4 = 0; k4 < 128; k4++) {
      float4 wv = Wv4[k4];
      acc += u_s[h][k4 * 4 + 0] * wv.x + u_s[h][k4 * 4 + 1] * wv.y +
             u_s[h][k4 * 4 + 2] * wv.z + u_s[h][k4 * 4 + 3] * wv.w;
    }
    ao_s[col] = acc;
  }
  __syncthreads();

  // ---- last = ao @ Wo^T + bo ----
#pragma unroll
  for (int pass = 0; pass < 2; pass++) {
    int j = tid + pass * 256;
    float acc = bo[j];
    const float4* Wo4 = (const float4*)(Wo + j * 512);
    for (int k4 = 0; k4 < 128; k4++) {
      float4 wv = Wo4[k4];
      acc += ao_s[k4 * 4 + 0] * wv.x + ao_s[k4 * 4 + 1] * wv.y +
             ao_s[k4 * 4 + 2] * wv.z + ao_s[k4 * 4 + 3] * wv.w;
    }
    last_s[j] = acc;
  }
  __syncthreads();

  // ---- collapsed GAT layer 1 ----
  const int j = tid;
  float acc = 0.f;
  for (int k = 0; k < 512; k++) acc += last_s[k] * W1[k * 256 + j];
  float u = (acc + b1[j]) * BN_INV_F * g1[j] + be1[j];
  float h1 = u > 0.f ? u : expm1f(u);
  h_s2[j] = h1;
  __syncthreads();

  // ---- collapsed GAT layer 2 ----
  float acc2 = 0.f;
  for (int k = 0; k < 256; k++) acc2 += h_s2[k] * W2[k * 256 + j];
  float u2 = (acc2 + pb2[j]) * BN_INV_F * g2[j] + be2[j];
  float sp = u2 > 0.f ? u2 : expm1f(u2);
  __syncthreads();
  h_s2[j] = sp;
  __syncthreads();

  // ---- fusion Linear ----
  float f = bfv[j];
  const float4* Wf4 = (const float4*)(Wf + j * 768);
  for (int k4 = 0; k4 < 128; k4++) {
    float4 wv = Wf4[k4];
    f += last_s[k4 * 4 + 0] * wv.x + last_s[k4 * 4 + 1] * wv.y +
         last_s[k4 * 4 + 2] * wv.z + last_s[k4 * 4 + 3] * wv.w;
  }
  for (int k4 = 0; k4 < 64; k4++) {
    float4 wv = Wf4[128 + k4];
    f += h_s2[k4 * 4 + 0] * wv.x + h_s2[k4 * 4 + 1] * wv.y +
         h_s2[k4 * 4 + 2] * wv.z + h_s2[k4 * 4 + 3] * wv.w;
  }

  // ---- LayerNorm + ReLU ----
  float v = f;
#pragma unroll
  for (int o = 32; o > 0; o >>= 1) v += __shfl_xor(v, o);
  if ((tid & 63) == 0) red_s[tid >> 6] = v;
  __syncthreads();
  float mu = (red_s[0] + red_s[1] + red_s[2] + red_s[3]) * (1.f / 256.f);
  float dv = f - mu;
  float vv = dv * dv;
#pragma unroll
  for (int o = 32; o > 0; o >>= 1) vv += __shfl_xor(vv, o);
  __syncthreads();
  if ((tid & 63) == 0) red_s[tid >> 6] = vv;
  __syncthreads();
  float var = (red_s[0] + red_s[1] + red_s[2] + red_s[3]) * (1.f / 256.f);
  float y = dv * rsqrtf(var + 1e-5f) * ln_g[j] + ln_b[j];
  dout[b * 256 + j] = fmaxf(y, 0.f);
}

// ---------------------------------------------------------------------------
// ws layout (bytes):
//   0         hbuf  [128][2][16][128] u32  2097152  (memset 0xFF each call)
//   2097152   tb    [16][128][512] bf16    2097152
//   4194304   Q     [2048][512] bf16       2097152
//   6291456   K     [2048][512] bf16       2097152
//   8388608   Wqb   [512][512]  bf16        524288
//   8912896   Wkb                           524288  -> total 9437184 bytes
// ---------------------------------------------------------------------------
extern "C" void kernel_launch(void* const* d_in, const int* in_sizes, int n_in,
                              void* d_out, int out_size, void* d_ws, size_t ws_size,
                              hipStream_t stream) {
  (void)in_sizes; (void)n_in; (void)out_size; (void)ws_size;
  const float* x     = (const float*)d_in[0];
  const float* Wih_f = (const float*)d_in[2];
  const float* Whh_f = (const float*)d_in[3];
  const float* bih_f = (const float*)d_in[4];
  const float* bhh_f = (const float*)d_in[5];
  const float* Wih_b = (const float*)d_in[6];
  const float* Whh_b = (const float*)d_in[7];
  const float* bih_b = (const float*)d_in[8];
  const float* bhh_b = (const float*)d_in[9];
  const float* Wq = (const float*)d_in[10]; const float* bq = (const float*)d_in[11];
  const float* Wk = (const float*)d_in[12]; const float* bk = (const float*)d_in[13];
  const float* Wv = (const float*)d_in[14]; const float* bv = (const float*)d_in[15];
  const float* Wo = (const float*)d_in[16]; const float* bo = (const float*)d_in[17];
  const float* W1 = (const float*)d_in[18];
  const float* b1 = (const float*)d_in[21];
  const float* g1 = (const float*)d_in[22]; const float* be1 = (const float*)d_in[23];
  const float* W2 = (const float*)d_in[24];
  const float* pb2 = (const float*)d_in[27];
  const float* g2 = (const float*)d_in[28]; const float* be2 = (const float*)d_in[29];
  const float* Wf = (const float*)d_in[30]; const float* bfv = (const float*)d_in[31];
  const float* ln_g = (const float*)d_in[32]; const float* ln_b = (const float*)d_in[33];

  float* dout = (float*)d_out;
  char* ws = (char*)d_ws;
  u32* hbuf = (u32*)(ws + 0);
  u16* tb   = (u16*)(ws + 2097152);
  u16* Qb   = (u16*)(ws + 4194304);
  u16* Kb   = (u16*)(ws + 6291456);
  u16* Wqb  = (u16*)(ws + 8388608);
  u16* Wkb  = (u16*)(ws + 8912896);

  (void)hipMemsetAsync(ws, 0xFF, 2097152, stream);  // poison hbuf ring
  lstm_kernel<<<64, 256, 0, stream>>>(x, Wih_f, Whh_f, bih_f, bhh_f,
                                      Wih_b, Whh_b, bih_b, bhh_b,
                                      Wq, Wk, Wqb, Wkb, hbuf, tb);
  qk_kernel<<<dim3(32, 8, 2), 256, 0, stream>>>(tb, Wqb, bq, Wkb, bk, Qb, Kb);
  attn_kernel<<<dim3(16, 4, 2), 256, 0, stream>>>(Qb, Kb, dout + 4096);
  tail_kernel<<<16, 256, 0, stream>>>(dout + 4096, tb, Wv, bv, Wo, bo,
                                      W1, b1, g1, be1, W2, pb2, g2, be2,
                                      Wf, bfv, ln_g, ln_b, dout);
}